// Round 17
// baseline (22.888 us; speedup 1.0000x reference)
//
#include <hip/hip_runtime.h>
#include <hip/hip_bf16.h>
#include <cstdint>

#define K_V_C   1.05f
#define G_DIFF  4.0e-4f   // G_MAX - G_MIN
#define KPW     4096      // k = 4*j + level (level 3 = zero pad), j = 0..1023

typedef __attribute__((ext_vector_type(8))) short short8;
typedef __attribute__((ext_vector_type(4))) float f32x4;

// I_REF rows 1..3 (row 0 is all zeros)
__device__ __constant__ float c_I1[9] = {-0.00015f,-0.00011f,-7e-05f,-3e-05f,0.f,3e-05f,7e-05f,0.00011f,0.00015f};
__device__ __constant__ float c_I2[9] = {-0.0005f,-0.00035f,-0.00022f,-9e-05f,0.f,9e-05f,0.00022f,0.00035f,0.0005f};
__device__ __constant__ float c_I3[9] = {-0.0009f,-0.0006f,-0.00037f,-0.00015f,0.f,0.00015f,0.00037f,0.0006f,0.0009f};

__device__ inline unsigned short f2bf(float f) {   // fp32 -> bf16 RNE
  unsigned int u = __float_as_uint(f);
  u += 0x7FFFu + ((u >> 16) & 1u);
  return (unsigned short)(u >> 16);
}

__device__ inline void interp3(float v, float& u1, float& u2, float& u3) {
  const float sf = v * 3.3333333333333335f + 4.0f;   // (v+1.2)/0.3
  float fs = floorf(sf);
  fs = fminf(fmaxf(fs, 0.f), 7.f);
  const int   s  = (int)fs;
  const float fr = fminf(fmaxf(sf - fs, 0.f), 1.f);
  u1 = fmaf(fr, c_I1[s+1] - c_I1[s], c_I1[s]);
  u2 = fmaf(fr, c_I2[s+1] - c_I2[s], c_I2[s]);
  u3 = fmaf(fr, c_I3[s+1] - c_I3[s], c_I3[s]);
}

// branch-free coeff3: clamped ramps, differences, sign OR'd in.
__device__ inline void coeff3f(float g, float& c1, float& c2, float& c3) {
  const float    ga = fabsf(g);
  const unsigned sb = __float_as_uint(g) & 0x80000000u;
  const float t1 = fminf(ga * 1e4f, 1.f);
  const float t2 = fminf(fmaxf((ga - 1e-4f) * 5e3f, 0.f), 1.f);
  const float t3 = fmaxf((ga - 3e-4f) * 5e3f, 0.f);
  c1 = __uint_as_float(__float_as_uint(t1 - t2) | sb);
  c2 = __uint_as_float(__float_as_uint(t2 - t3) | sb);
  c3 = __uint_as_float(__float_as_uint(t3) | sb);
}

__device__ inline void coeff3(float g, float& c1, float& c2, float& c3) {
  const float ga  = fabsf(g);
  const float sgn = (g > 0.f) ? 1.f : ((g < 0.f) ? -1.f : 0.f);
  const int   idx = (ga >= 3e-4f) ? 2 : ((ga >= 1e-4f) ? 1 : 0);
  const float g0   = (idx == 0) ? 0.f : ((idx == 1) ? 1e-4f : 3e-4f);
  const float invd = (idx == 0) ? 1e4f : 5e3f;
  const float t    = (ga - g0) * invd;
  const float clo = sgn * (1.f - t), chi = sgn * t;
  c1 = (idx == 0) ? chi : ((idx == 1) ? clo : 0.f);
  c2 = (idx == 1) ? chi : ((idx == 2) ? clo : 0.f);
  c3 = (idx == 2) ? chi : 0.f;
}

__device__ inline float wave_maxw(const float* __restrict__ partials, int lane) {
  float mx = 0.f;
  #pragma unroll
  for (int i = 0; i < 4; ++i) {
    const float4 p = ((const float4*)partials)[lane + i * 64];
    mx = fmaxf(mx, fmaxf(fmaxf(p.x, p.y), fmaxf(p.z, p.w)));
  }
  #pragma unroll
  for (int o = 1; o < 64; o <<= 1) mx = fmaxf(mx, __shfl_xor(mx, o, 64));
  return mx;
}

// ---------------------------------------------------------------------------
// Dispatch 1: blocks 0..1023  -> per-block max(|w|,|b|) partials (no atomics)
//             blocks 1024..1151 -> prep U bf16 [128][KPW], k = 4*j+lvl, j<1024
// ---------------------------------------------------------------------------
__global__ __launch_bounds__(256) void prep1_kernel(
    const float* __restrict__ x, const float* __restrict__ w,
    const float* __restrict__ bias, float* __restrict__ partials,
    unsigned short* __restrict__ Ub) {
  const int t = threadIdx.x, bid = blockIdx.x;
  if (bid < 1024) {                       // ---- maxabs partial ----
    const int i = bid * 256 + t;          // one float4 of w per thread
    const float4 v = ((const float4*)w)[i];
    float m = fmaxf(fmaxf(fabsf(v.x), fabsf(v.y)), fmaxf(fabsf(v.z), fabsf(v.w)));
    if (i < 256) {
      const float4 bv = ((const float4*)bias)[i];
      m = fmaxf(m, fmaxf(fmaxf(fabsf(bv.x), fabsf(bv.y)),
                         fmaxf(fabsf(bv.z), fabsf(bv.w))));
    }
    #pragma unroll
    for (int o = 32; o > 0; o >>= 1) m = fmaxf(m, __shfl_down(m, o, 64));
    __shared__ float red[4];
    if ((t & 63) == 0) red[t >> 6] = m;
    __syncthreads();
    if (t == 0)
      partials[bid] = fmaxf(fmaxf(red[0], red[1]), fmaxf(red[2], red[3]));
  } else {                                // ---- prep U (no bias column) ----
    const int idx = (bid - 1024) * 256 + t;   // 32768 = 128 b x 256 j4-groups
    const int b = idx >> 8, j4 = idx & 255;
    const float4 xv = ((const float4*)x)[b * 256 + j4];
    float u1, u2, u3;
    ushort4* dst = (ushort4*)(Ub + (size_t)b * KPW + j4 * 16);
    interp3(K_V_C * xv.x, u1, u2, u3); dst[0] = make_ushort4(f2bf(u1), f2bf(u2), f2bf(u3), 0);
    interp3(K_V_C * xv.y, u1, u2, u3); dst[1] = make_ushort4(f2bf(u1), f2bf(u2), f2bf(u3), 0);
    interp3(K_V_C * xv.z, u1, u2, u3); dst[2] = make_ushort4(f2bf(u1), f2bf(u2), f2bf(u3), 0);
    interp3(K_V_C * xv.w, u1, u2, u3); dst[3] = make_ushort4(f2bf(u1), f2bf(u2), f2bf(u3), 0);
  }
}

// ---------------------------------------------------------------------------
// Dispatch 2: blocked GEMM. 256 blocks x 1024 thr. Block = 128 b x 64 m x
//   256 k brick: mt = bid&15 (m0 = mt*64), kt = bid>>4 (k0 = kt*256).
//   16 waves = 4 m-subtiles (ms) x 4 k-subslices (ks2). Two k-halves of 128:
//   stage A-half U[128][128] bf16 -> Alds[128][136] (16B-aligned rows, 2-way
//   banks) and w-half [32 j][64 m] -> wlds[32][68] f32; per wave per half:
//   ONE B-fragment build (2 coeff3f) feeds 8 MFMAs (b-subtiles). Epilogue:
//   4 unrolled rounds reduce the 4 ks2-waves per ms via LDS (aliases Alds)
//   and write unscaled partials to slab[kt][128][1024].
// ---------------------------------------------------------------------------
__global__ __launch_bounds__(1024, 4) void gemm2_kernel(
    const float* __restrict__ w, const float* __restrict__ partials,
    const unsigned short* __restrict__ Ub, float* __restrict__ slab) {
  __shared__ __align__(16) unsigned short Alds[128 * 136];   // 34.8 KB
  __shared__ __align__(16) float wlds[32 * 68];              //  8.7 KB
  const int t = threadIdx.x;
  const int wv = t >> 6, lane = t & 63, la = lane & 15, kg = lane >> 4;
  const int ms = wv >> 2, ks2 = wv & 3;
  const int m0 = (blockIdx.x & 15) * 64;
  const int kt = blockIdx.x >> 4;
  const int k0 = kt * 256, j0 = kt * 64;

  const float maxw = wave_maxw(partials, lane);
  const float kG   = G_DIFF / maxw;

  f32x4 acc[8];
  #pragma unroll
  for (int bs = 0; bs < 8; ++bs) acc[bs] = (f32x4){0.f, 0.f, 0.f, 0.f};

  #pragma unroll
  for (int h = 0; h < 2; ++h) {
    __syncthreads();                           // prev half fully consumed
    // ---- stage A-half: Ub[0..127][k0+h*128 .. +127] -> Alds[128][136] ----
    #pragma unroll
    for (int i = 0; i < 4; ++i) {
      const int idx = i * 1024 + t;            // 4096 ushort4
      const int r = idx >> 5, c = idx & 31;
      *(ushort4*)&Alds[r * 136 + c * 4] =
          *(const ushort4*)(Ub + (size_t)r * KPW + k0 + h * 128 + c * 4);
    }
    // ---- stage w-half: w[j0+h*32 .. +31][m0..m0+63] -> wlds[32][68] ----
    if (t < 512) {
      const int j = t >> 4, c = t & 15;
      *(float4*)&wlds[j * 68 + c * 4] =
          *(const float4*)(w + (size_t)(j0 + h * 32 + j) * 1024 + m0 + c * 4);
    }
    __syncthreads();
    // ---- one B-build + 8 MFMA per wave ----
    const int jh = ks2 * 8 + kg * 2;           // local j pair: jh, jh+1
    const float w0 = wlds[jh * 68 + ms * 16 + la];
    const float w1 = wlds[(jh + 1) * 68 + ms * 16 + la];
    float a1, a2, a3, b1, b2, b3;
    coeff3f(kG * w0, a1, a2, a3);
    coeff3f(kG * w1, b1, b2, b3);
    union { __hip_bfloat162 hh[4]; short8 s; } bf;
    bf.hh[0] = __float22bfloat162_rn(make_float2(a1, a2));
    bf.hh[1] = __float22bfloat162_rn(make_float2(a3, 0.f));
    bf.hh[2] = __float22bfloat162_rn(make_float2(b1, b2));
    bf.hh[3] = __float22bfloat162_rn(make_float2(b3, 0.f));
    const int kloc = ks2 * 32 + kg * 8;
    #pragma unroll
    for (int bs = 0; bs < 8; ++bs) {
      const short8 a = *(const short8*)&Alds[(bs * 16 + la) * 136 + kloc];
      acc[bs] = __builtin_amdgcn_mfma_f32_16x16x32_bf16(a, bf.s, acc[bs], 0, 0, 0);
    }
  }

  // ---- epilogue: reduce 4 ks2-waves per ms, write slab[kt] partials ----
  float* P = (float*)Alds;                     // 32 KB, aliased after barrier
  float* sl = slab + (size_t)kt * 131072;
  #pragma unroll
  for (int r = 0; r < 4; ++r) {
    __syncthreads();                           // Alds reads done / P consumed
    *(float4*)&P[wv * 512 + lane * 4]       = make_float4(acc[2*r][0], acc[2*r][1], acc[2*r][2], acc[2*r][3]);
    *(float4*)&P[wv * 512 + 256 + lane * 4] = make_float4(acc[2*r+1][0], acc[2*r+1][1], acc[2*r+1][2], acc[2*r+1][3]);
    __syncthreads();
    const int ms2 = t >> 8, f = t & 255;
    float s0 = 0.f, s1 = 0.f;
    #pragma unroll
    for (int k2 = 0; k2 < 4; ++k2) {
      s0 += P[(ms2 * 4 + k2) * 512 + f];
      s1 += P[(ms2 * 4 + k2) * 512 + 256 + f];
    }
    const int row = ((f >> 6) << 2) + (f & 3); // D: row = kg*4+reg
    const int col = (f >> 2) & 15;             //    col = lane&15
    const int bg  = r * 32 + row;
    sl[(size_t)bg * 1024 + m0 + ms2 * 16 + col]        = s0;
    sl[(size_t)(bg + 16) * 1024 + m0 + ms2 * 16 + col] = s1;
  }
}

// ---------------------------------------------------------------------------
// Dispatch 3: sum 16 slabs + f32 bias rank-1 term + scale -> out (full write).
// ---------------------------------------------------------------------------
__global__ __launch_bounds__(256) void reduce2_kernel(
    const float* __restrict__ partials, const float* __restrict__ bias,
    const float* __restrict__ slab, float* __restrict__ out) {
  const int t = threadIdx.x;
  const int i = blockIdx.x * 256 + t;          // 32768 float4 of out
  const float maxw  = wave_maxw(partials, t & 63);
  const float kG    = G_DIFF / maxw;
  const float scale = maxw * (1.0f / (K_V_C * G_DIFF));
  const int b = i >> 8, m4 = (i & 255) * 4;

  float sx = 0.f, sy = 0.f, sz = 0.f, sw = 0.f;
  #pragma unroll
  for (int kt = 0; kt < 16; ++kt) {
    const float4 v = *(const float4*)(slab + (size_t)kt * 131072 + b * 1024 + m4);
    sx += v.x; sy += v.y; sz += v.z; sw += v.w;
  }
  float u1, u2, u3;
  interp3(K_V_C, u1, u2, u3);                  // ones-column currents
  const float4 bv = *(const float4*)(bias + m4);
  float c1, c2, c3;
  coeff3f(kG * bv.x, c1, c2, c3); sx += c1*u1 + c2*u2 + c3*u3;
  coeff3f(kG * bv.y, c1, c2, c3); sy += c1*u1 + c2*u2 + c3*u3;
  coeff3f(kG * bv.z, c1, c2, c3); sz += c1*u1 + c2*u2 + c3*u3;
  coeff3f(kG * bv.w, c1, c2, c3); sw += c1*u1 + c2*u2 + c3*u3;
  *(float4*)(out + b * 1024 + m4) =
      make_float4(sx * scale, sy * scale, sz * scale, sw * scale);
}

// ---------------------------------------------------------------------------
// Fallback (tiny ws): atomic-based path, needs only 4 bytes of ws.
// ---------------------------------------------------------------------------
__global__ __launch_bounds__(256) void maxabs_atomic_kernel(
    const float* __restrict__ w, const float* __restrict__ b,
    unsigned int* __restrict__ wsmax) {
  const int NW4 = 262144, NB4 = 256;
  float m = 0.f;
  for (int i = blockIdx.x * blockDim.x + threadIdx.x; i < NW4 + NB4;
       i += gridDim.x * blockDim.x) {
    float4 v = (i < NW4) ? ((const float4*)w)[i] : ((const float4*)b)[i - NW4];
    m = fmaxf(m, fmaxf(fmaxf(fabsf(v.x), fabsf(v.y)),
                       fmaxf(fabsf(v.z), fabsf(v.w))));
  }
  #pragma unroll
  for (int o = 32; o > 0; o >>= 1) m = fmaxf(m, __shfl_down(m, o, 64));
  __shared__ float red[4];
  if ((threadIdx.x & 63) == 0) red[threadIdx.x >> 6] = m;
  __syncthreads();
  if (threadIdx.x == 0)
    atomicMax(wsmax, __float_as_uint(fmaxf(fmaxf(red[0], red[1]),
                                           fmaxf(red[2], red[3]))));
}

__global__ __launch_bounds__(256) void memristor_atomic_kernel(
    const float* __restrict__ x, const float* __restrict__ w,
    const float* __restrict__ bias, const unsigned int* __restrict__ wsmax,
    float* __restrict__ out) {
  __shared__ float4 U[2048];
  const int tid = threadIdx.x;
  const float maxw  = __uint_as_float(*wsmax);
  const float kG    = G_DIFF / maxw;
  const float scale = maxw * (1.0f / (K_V_C * G_DIFF));
  const int mq = tid & 15, bg = tid >> 4;
  const int m0 = blockIdx.x * 64 + mq * 4;
  const int swz = bg & 7;
  float acc[4][8];
  #pragma unroll
  for (int a = 0; a < 4; ++a)
    #pragma unroll
    for (int c = 0; c < 8; ++c) acc[a][c] = 0.f;
  for (int sc = blockIdx.y; sc < 65; sc += 16) {
    const int j0 = sc * 16;
    const int nj = min(16, 1025 - j0);
    __syncthreads();
    #pragma unroll
    for (int k = 0; k < 8; ++k) {
      const int e = k * 256 + tid;
      const int jl = e & 15, b = e >> 4;
      const int jg = j0 + jl;
      if (jg <= 1024) {
        const float v = (jg < 1024) ? K_V_C * x[b * 1024 + jg] : K_V_C;
        float u1, u2, u3;
        interp3(v, u1, u2, u3);
        U[b * 16 + (jl ^ ((b >> 3) & 7))] = make_float4(0.f, u1, u2, u3);
      }
    }
    __syncthreads();
    for (int jl = 0; jl < nj; ++jl) {
      const int jg = j0 + jl;
      const float4 wv = (jg < 1024) ? *(const float4*)(w + jg * 1024 + m0)
                                    : *(const float4*)(bias + m0);
      const float warr[4] = {wv.x, wv.y, wv.z, wv.w};
      float c1[4], c2[4], c3[4];
      #pragma unroll
      for (int mi = 0; mi < 4; ++mi) coeff3(kG * warr[mi], c1[mi], c2[mi], c3[mi]);
      const int base = bg * 128 + (jl ^ swz);
      #pragma unroll
      for (int bb = 0; bb < 8; ++bb) {
        const float4 u = U[base + bb * 16];
        #pragma unroll
        for (int mi = 0; mi < 4; ++mi)
          acc[mi][bb] = fmaf(c1[mi], u.y, fmaf(c2[mi], u.z, fmaf(c3[mi], u.w, acc[mi][bb])));
      }
    }
  }
  #pragma unroll
  for (int bb = 0; bb < 8; ++bb) {
    const int b = bg * 8 + bb;
    #pragma unroll
    for (int mi = 0; mi < 4; ++mi)
      atomicAdd(&out[b * 1024 + m0 + mi], acc[mi][bb] * scale);
  }
}

// ---------------------------------------------------------------------------
extern "C" void kernel_launch(void* const* d_in, const int* in_sizes, int n_in,
                              void* d_out, int out_size, void* d_ws, size_t ws_size,
                              hipStream_t stream) {
  const float* x = (const float*)d_in[0];   // (128, 1024)
  const float* w = (const float*)d_in[1];   // (1024, 1024)
  const float* b = (const float*)d_in[2];   // (1024,)
  float* out = (float*)d_out;               // (128, 1024) fp32

  float*          partials = (float*)((char*)d_ws + 128);          // 1024 f32
  unsigned short* Ub   = (unsigned short*)((char*)d_ws + 65536);   // 1 MB
  float*          slab = (float*)((char*)d_ws + (2u << 20));       // 8 MB
  const size_t need = (2u << 20) + (size_t)16 * 131072 * sizeof(float); // 10 MB

  if (ws_size >= need) {
    prep1_kernel<<<1152, 256, 0, stream>>>(x, w, b, partials, Ub);
    gemm2_kernel<<<256, 1024, 0, stream>>>(w, partials, Ub, slab);
    reduce2_kernel<<<128, 256, 0, stream>>>(partials, b, slab, out);
  } else {                                 // fallback: tiny ws, atomic path
    unsigned int* wsmax = (unsigned int*)d_ws;
    hipMemsetAsync(wsmax, 0, 4, stream);
    maxabs_atomic_kernel<<<256, 256, 0, stream>>>(w, b, wsmax);
    hipMemsetAsync(out, 0, (size_t)out_size * sizeof(float), stream);
    dim3 grid(16, 16);
    memristor_atomic_kernel<<<grid, 256, 0, stream>>>(x, w, b, wsmax, out);
  }
}

// Round 20
// 22.359 us; speedup vs baseline: 1.0237x; 1.0237x over previous
//
#include <hip/hip_runtime.h>
#include <hip/hip_bf16.h>
#include <cstdint>

#define K_V_C   1.05f
#define G_DIFF  4.0e-4f   // G_MAX - G_MIN

typedef __attribute__((ext_vector_type(8))) short short8;
typedef __attribute__((ext_vector_type(4))) float f32x4;

// I_REF rows 1..3 (row 0 is all zeros)
__device__ __constant__ float c_I1[9] = {-0.00015f,-0.00011f,-7e-05f,-3e-05f,0.f,3e-05f,7e-05f,0.00011f,0.00015f};
__device__ __constant__ float c_I2[9] = {-0.0005f,-0.00035f,-0.00022f,-9e-05f,0.f,9e-05f,0.00022f,0.00035f,0.0005f};
__device__ __constant__ float c_I3[9] = {-0.0009f,-0.0006f,-0.00037f,-0.00015f,0.f,0.00015f,0.00037f,0.0006f,0.0009f};

__device__ inline unsigned short f2bf(float f) {   // fp32 -> bf16 RNE
  unsigned int u = __float_as_uint(f);
  u += 0x7FFFu + ((u >> 16) & 1u);
  return (unsigned short)(u >> 16);
}

__device__ inline float bf2f(unsigned short h) {
  return __uint_as_float((unsigned int)h << 16);
}

__device__ inline void interp3(float v, float& u1, float& u2, float& u3) {
  const float sf = v * 3.3333333333333335f + 4.0f;   // (v+1.2)/0.3
  float fs = floorf(sf);
  fs = fminf(fmaxf(fs, 0.f), 7.f);
  const int   s  = (int)fs;
  const float fr = fminf(fmaxf(sf - fs, 0.f), 1.f);
  u1 = fmaf(fr, c_I1[s+1] - c_I1[s], c_I1[s]);
  u2 = fmaf(fr, c_I2[s+1] - c_I2[s], c_I2[s]);
  u3 = fmaf(fr, c_I3[s+1] - c_I3[s], c_I3[s]);
}

// branch-free coeff3: clamped ramps, differences, sign OR'd in.
__device__ inline void coeff3f(float g, float& c1, float& c2, float& c3) {
  const float    ga = fabsf(g);
  const unsigned sb = __float_as_uint(g) & 0x80000000u;
  const float t1 = fminf(ga * 1e4f, 1.f);
  const float t2 = fminf(fmaxf((ga - 1e-4f) * 5e3f, 0.f), 1.f);
  const float t3 = fmaxf((ga - 3e-4f) * 5e3f, 0.f);
  c1 = __uint_as_float(__float_as_uint(t1 - t2) | sb);
  c2 = __uint_as_float(__float_as_uint(t2 - t3) | sb);
  c3 = __uint_as_float(__float_as_uint(t3) | sb);
}

__device__ inline void coeff3(float g, float& c1, float& c2, float& c3) {
  const float ga  = fabsf(g);
  const float sgn = (g > 0.f) ? 1.f : ((g < 0.f) ? -1.f : 0.f);
  const int   idx = (ga >= 3e-4f) ? 2 : ((ga >= 1e-4f) ? 1 : 0);
  const float g0   = (idx == 0) ? 0.f : ((idx == 1) ? 1e-4f : 3e-4f);
  const float invd = (idx == 0) ? 1e4f : 5e3f;
  const float t    = (ga - g0) * invd;
  const float clo = sgn * (1.f - t), chi = sgn * t;
  c1 = (idx == 0) ? chi : ((idx == 1) ? clo : 0.f);
  c2 = (idx == 1) ? chi : ((idx == 2) ? clo : 0.f);
  c3 = (idx == 2) ? chi : 0.f;
}

// ---------------------------------------------------------------------------
// Dispatch 1: per-block max(|w|,|b|) partials only (no atomics). 1024 blocks.
// ---------------------------------------------------------------------------
__global__ __launch_bounds__(256) void maxabs_kernel(
    const float* __restrict__ w, const float* __restrict__ bias,
    float* __restrict__ partials) {
  const int t = threadIdx.x, bid = blockIdx.x;
  const int i = bid * 256 + t;            // one float4 of w per thread
  const float4 v = ((const float4*)w)[i];
  float m = fmaxf(fmaxf(fabsf(v.x), fabsf(v.y)), fmaxf(fabsf(v.z), fabsf(v.w)));
  if (i < 256) {
    const float4 bv = ((const float4*)bias)[i];
    m = fmaxf(m, fmaxf(fmaxf(fabsf(bv.x), fabsf(bv.y)),
                       fmaxf(fabsf(bv.z), fabsf(bv.w))));
  }
  #pragma unroll
  for (int o = 32; o > 0; o >>= 1) m = fmaxf(m, __shfl_down(m, o, 64));
  __shared__ float red[4];
  if ((t & 63) == 0) red[t >> 6] = m;
  __syncthreads();
  if (t == 0)
    partials[bid] = fmaxf(fmaxf(red[0], red[1]), fmaxf(red[2], red[3]));
}

// ---------------------------------------------------------------------------
// Dispatch 2: wide-N GEMM with BOTH operand fragments built on the fly.
//   256 blocks (16 b x 32 m tile) x 16 waves, split-K x16 (72 j per wave,
//   9 MFMA steps). Per step: A-frag = interp3 of 2 x-values (LDS table) in
//   registers; B-frags = coeff3f of 4 panel weights. No U tensor anywhere.
//   bf16 panel [1152 j][32 m] (72 KB; row 1024 = bias, 1025+ = 0).
//   P[16][512] f32 (32 KB) aliases the panel for the K-reduce.
// ---------------------------------------------------------------------------
__global__ __launch_bounds__(1024, 4) void fusedgemm_kernel(
    const float* __restrict__ x, const float* __restrict__ w,
    const float* __restrict__ bias, const float* __restrict__ partials,
    float* __restrict__ out) {
  __shared__ __align__(16) unsigned short panel[36864];   // 72 KB: [1152][32]
  __shared__ __align__(16) float4 T0s[8], TDs[8];         // interp tables
  const int t = threadIdx.x;
  const int wv = t >> 6, lane = t & 63, la = lane & 15, kg = lane >> 4;
  const int b0 = (blockIdx.x >> 5) * 16;
  const int n0 = (blockIdx.x & 31) * 32;

  if (t < 8) {
    T0s[t] = make_float4(c_I1[t], c_I2[t], c_I3[t], 0.f);
    TDs[t] = make_float4(c_I1[t+1] - c_I1[t], c_I2[t+1] - c_I2[t],
                         c_I3[t+1] - c_I3[t], 0.f);
  }

  // ---- stage bf16 w-panel: panel[j][mm] = bf16(w[j][n0+mm]) ----
  #pragma unroll
  for (int i = 0; i < 8; ++i) {
    const int idx = i * 1024 + t;              // 8192 float4 of the w panel
    const int row = idx >> 3, c4 = idx & 7;    // row = j, 8 f4 per row
    const float4 v = *(const float4*)(w + (size_t)row * 1024 + n0 + c4 * 4);
    *(ushort4*)&panel[row * 32 + c4 * 4] =
        make_ushort4(f2bf(v.x), f2bf(v.y), f2bf(v.z), f2bf(v.w));
  }
  if (t < 32) panel[1024 * 32 + t] = f2bf(bias[n0 + t]);   // row 1024 = bias
  for (int i = 1025 * 32 + t; i < 1152 * 32; i += 1024) panel[i] = 0;

  // ---- maxw from all 1024 partials ----
  float mx = 0.f;
  #pragma unroll
  for (int i = 0; i < 4; ++i) {
    const float4 p = ((const float4*)partials)[lane + i * 64];
    mx = fmaxf(mx, fmaxf(fmaxf(p.x, p.y), fmaxf(p.z, p.w)));
  }
  #pragma unroll
  for (int o = 1; o < 64; o <<= 1) mx = fmaxf(mx, __shfl_xor(mx, o, 64));
  const float maxw = mx;
  const float kG   = G_DIFF / maxw;
  __syncthreads();

  // ---- 9-step MFMA loop; A and B fragments both built on the fly ----
  const float* xrow = x + (size_t)(b0 + la) * 1024;
  const int jb = wv * 72 + kg * 2;
  f32x4 acc0 = {0.f, 0.f, 0.f, 0.f};
  f32x4 acc1 = {0.f, 0.f, 0.f, 0.f};
  #pragma unroll 3
  for (int ks = 0; ks < 9; ++ks) {
    const int j0 = jb + ks * 8;                // this lane's two j's: j0, j0+1
    // ---- A-fragment: currents for x[b0+la][j0], x[b0+la][j0+1] ----
    const float xa = (j0     < 1024) ? xrow[min(j0, 1023)]     : 1.0f;
    const float xb = (j0 + 1 < 1024) ? xrow[min(j0 + 1, 1023)] : 1.0f;
    float u1, u2, u3, v1, v2, v3;
    {
      const float sf = (K_V_C * xa) * 3.3333333333333335f + 4.0f;
      float fs = fminf(fmaxf(floorf(sf), 0.f), 7.f);
      const int s = (int)fs;
      const float fr = fminf(fmaxf(sf - fs, 0.f), 1.f);
      const float4 y0 = T0s[s], dy = TDs[s];
      u1 = fmaf(fr, dy.x, y0.x); u2 = fmaf(fr, dy.y, y0.y); u3 = fmaf(fr, dy.z, y0.z);
    }
    {
      const float sf = (K_V_C * xb) * 3.3333333333333335f + 4.0f;
      float fs = fminf(fmaxf(floorf(sf), 0.f), 7.f);
      const int s = (int)fs;
      const float fr = fminf(fmaxf(sf - fs, 0.f), 1.f);
      const float4 y0 = T0s[s], dy = TDs[s];
      v1 = fmaf(fr, dy.x, y0.x); v2 = fmaf(fr, dy.y, y0.y); v3 = fmaf(fr, dy.z, y0.z);
    }
    if (j0 > 1024)     { u1 = 0.f; u2 = 0.f; u3 = 0.f; }   // zero-pad rows
    if (j0 + 1 > 1024) { v1 = 0.f; v2 = 0.f; v3 = 0.f; }
    union { __hip_bfloat162 h[4]; short8 s; } af;
    af.h[0] = __float22bfloat162_rn(make_float2(u1, u2));
    af.h[1] = __float22bfloat162_rn(make_float2(u3, 0.f));
    af.h[2] = __float22bfloat162_rn(make_float2(v1, v2));
    af.h[3] = __float22bfloat162_rn(make_float2(v3, 0.f));
    // ---- B-fragments from the LDS panel ----
    const float w0a = bf2f(panel[j0 * 32 + la]);
    const float w0b = bf2f(panel[(j0 + 1) * 32 + la]);
    const float w1a = bf2f(panel[j0 * 32 + 16 + la]);
    const float w1b = bf2f(panel[(j0 + 1) * 32 + 16 + la]);
    float a1, a2, a3, b1, b2, b3, c1, c2, c3, d1, d2, d3;
    coeff3f(kG * w0a, a1, a2, a3);
    coeff3f(kG * w0b, b1, b2, b3);
    coeff3f(kG * w1a, c1, c2, c3);
    coeff3f(kG * w1b, d1, d2, d3);
    union { __hip_bfloat162 h[4]; short8 s; } bf0, bf1;
    bf0.h[0] = __float22bfloat162_rn(make_float2(a1, a2));
    bf0.h[1] = __float22bfloat162_rn(make_float2(a3, 0.f));
    bf0.h[2] = __float22bfloat162_rn(make_float2(b1, b2));
    bf0.h[3] = __float22bfloat162_rn(make_float2(b3, 0.f));
    bf1.h[0] = __float22bfloat162_rn(make_float2(c1, c2));
    bf1.h[1] = __float22bfloat162_rn(make_float2(c3, 0.f));
    bf1.h[2] = __float22bfloat162_rn(make_float2(d1, d2));
    bf1.h[3] = __float22bfloat162_rn(make_float2(d3, 0.f));
    acc0 = __builtin_amdgcn_mfma_f32_16x16x32_bf16(af.s, bf0.s, acc0, 0, 0, 0);
    acc1 = __builtin_amdgcn_mfma_f32_16x16x32_bf16(af.s, bf1.s, acc1, 0, 0, 0);
  }

  // ---- cross-wave K-reduce (P aliases the panel) + fused scale ----
  float* P = (float*)panel;                    // 32 KB < 72 KB, after barrier
  __syncthreads();                             // all waves done reading panel
  *(float4*)&P[wv * 512 + lane * 4]       = make_float4(acc0[0], acc0[1], acc0[2], acc0[3]);
  *(float4*)&P[wv * 512 + 256 + lane * 4] = make_float4(acc1[0], acc1[1], acc1[2], acc1[3]);
  __syncthreads();
  if (t < 512) {
    float s = 0.f;
    #pragma unroll
    for (int ww = 0; ww < 16; ++ww) s += P[ww * 512 + t];
    const int frag = t >> 8, f = t & 255;
    const int l2 = f >> 2, ai = f & 3;         // D: col = lane&15, row = kg*4+r
    const int row = b0 + ((l2 >> 4) << 2) + ai;
    const int col = n0 + frag * 16 + (l2 & 15);
    out[(size_t)row * 1024 + col] = s * (maxw * (1.0f / (K_V_C * G_DIFF)));
  }
}

// ---------------------------------------------------------------------------
// Fallback (tiny ws): atomic-based path, needs only 4 bytes of ws.
// ---------------------------------------------------------------------------
__global__ __launch_bounds__(256) void maxabs_atomic_kernel(
    const float* __restrict__ w, const float* __restrict__ b,
    unsigned int* __restrict__ wsmax) {
  const int NW4 = 262144, NB4 = 256;
  float m = 0.f;
  for (int i = blockIdx.x * blockDim.x + threadIdx.x; i < NW4 + NB4;
       i += gridDim.x * blockDim.x) {
    float4 v = (i < NW4) ? ((const float4*)w)[i] : ((const float4*)b)[i - NW4];
    m = fmaxf(m, fmaxf(fmaxf(fabsf(v.x), fabsf(v.y)),
                       fmaxf(fabsf(v.z), fabsf(v.w))));
  }
  #pragma unroll
  for (int o = 32; o > 0; o >>= 1) m = fmaxf(m, __shfl_down(m, o, 64));
  __shared__ float red[4];
  if ((threadIdx.x & 63) == 0) red[threadIdx.x >> 6] = m;
  __syncthreads();
  if (threadIdx.x == 0)
    atomicMax(wsmax, __float_as_uint(fmaxf(fmaxf(red[0], red[1]),
                                           fmaxf(red[2], red[3]))));
}

__global__ __launch_bounds__(256) void memristor_atomic_kernel(
    const float* __restrict__ x, const float* __restrict__ w,
    const float* __restrict__ bias, const unsigned int* __restrict__ wsmax,
    float* __restrict__ out) {
  __shared__ float4 U[2048];
  const int tid = threadIdx.x;
  const float maxw  = __uint_as_float(*wsmax);
  const float kG    = G_DIFF / maxw;
  const float scale = maxw * (1.0f / (K_V_C * G_DIFF));
  const int mq = tid & 15, bg = tid >> 4;
  const int m0 = blockIdx.x * 64 + mq * 4;
  const int swz = bg & 7;
  float acc[4][8];
  #pragma unroll
  for (int a = 0; a < 4; ++a)
    #pragma unroll
    for (int c = 0; c < 8; ++c) acc[a][c] = 0.f;
  for (int sc = blockIdx.y; sc < 65; sc += 16) {
    const int j0 = sc * 16;
    const int nj = min(16, 1025 - j0);
    __syncthreads();
    #pragma unroll
    for (int k = 0; k < 8; ++k) {
      const int e = k * 256 + tid;
      const int jl = e & 15, b = e >> 4;
      const int jg = j0 + jl;
      if (jg <= 1024) {
        const float v = (jg < 1024) ? K_V_C * x[b * 1024 + jg] : K_V_C;
        float u1, u2, u3;
        interp3(v, u1, u2, u3);
        U[b * 16 + (jl ^ ((b >> 3) & 7))] = make_float4(0.f, u1, u2, u3);
      }
    }
    __syncthreads();
    for (int jl = 0; jl < nj; ++jl) {
      const int jg = j0 + jl;
      const float4 wv = (jg < 1024) ? *(const float4*)(w + jg * 1024 + m0)
                                    : *(const float4*)(bias + m0);
      const float warr[4] = {wv.x, wv.y, wv.z, wv.w};
      float c1[4], c2[4], c3[4];
      #pragma unroll
      for (int mi = 0; mi < 4; ++mi) coeff3(kG * warr[mi], c1[mi], c2[mi], c3[mi]);
      const int base = bg * 128 + (jl ^ swz);
      #pragma unroll
      for (int bb = 0; bb < 8; ++bb) {
        const float4 u = U[base + bb * 16];
        #pragma unroll
        for (int mi = 0; mi < 4; ++mi)
          acc[mi][bb] = fmaf(c1[mi], u.y, fmaf(c2[mi], u.z, fmaf(c3[mi], u.w, acc[mi][bb])));
      }
    }
  }
  #pragma unroll
  for (int bb = 0; bb < 8; ++bb) {
    const int b = bg * 8 + bb;
    #pragma unroll
    for (int mi = 0; mi < 4; ++mi)
      atomicAdd(&out[b * 1024 + m0 + mi], acc[mi][bb] * scale);
  }
}

// ---------------------------------------------------------------------------
extern "C" void kernel_launch(void* const* d_in, const int* in_sizes, int n_in,
                              void* d_out, int out_size, void* d_ws, size_t ws_size,
                              hipStream_t stream) {
  const float* x = (const float*)d_in[0];   // (128, 1024)
  const float* w = (const float*)d_in[1];   // (1024, 1024)
  const float* b = (const float*)d_in[2];   // (1024,)
  float* out = (float*)d_out;               // (128, 1024) fp32

  float* partials = (float*)((char*)d_ws + 128);   // 1024 f32
  const size_t need = 128 + 1024 * sizeof(float);  // ~4.2 KB

  if (ws_size >= need) {
    maxabs_kernel<<<1024, 256, 0, stream>>>(w, b, partials);
    fusedgemm_kernel<<<256, 1024, 0, stream>>>(x, w, b, partials, out);
  } else {                                 // fallback: tiny ws, atomic path
    unsigned int* wsmax = (unsigned int*)d_ws;
    hipMemsetAsync(wsmax, 0, 4, stream);
    maxabs_atomic_kernel<<<256, 256, 0, stream>>>(w, b, wsmax);
    hipMemsetAsync(out, 0, (size_t)out_size * sizeof(float), stream);
    dim3 grid(16, 16);
    memristor_atomic_kernel<<<grid, 256, 0, stream>>>(x, w, b, wsmax, out);
  }
}

// Round 21
// 18.132 us; speedup vs baseline: 1.2623x; 1.2331x over previous
//
#include <hip/hip_runtime.h>
#include <hip/hip_bf16.h>
#include <cstdint>

#define K_V_C   1.05f
#define G_DIFF  4.0e-4f   // G_MAX - G_MIN
#define KP4     4608      // k = 4*j + level (level 3 = zero pad), j padded to 1152

typedef __attribute__((ext_vector_type(8))) short short8;
typedef __attribute__((ext_vector_type(4))) float f32x4;

// I_REF rows 1..3 (row 0 is all zeros)
__device__ __constant__ float c_I1[9] = {-0.00015f,-0.00011f,-7e-05f,-3e-05f,0.f,3e-05f,7e-05f,0.00011f,0.00015f};
__device__ __constant__ float c_I2[9] = {-0.0005f,-0.00035f,-0.00022f,-9e-05f,0.f,9e-05f,0.00022f,0.00035f,0.0005f};
__device__ __constant__ float c_I3[9] = {-0.0009f,-0.0006f,-0.00037f,-0.00015f,0.f,0.00015f,0.00037f,0.0006f,0.0009f};

__device__ inline unsigned short f2bf(float f) {   // fp32 -> bf16 RNE
  unsigned int u = __float_as_uint(f);
  u += 0x7FFFu + ((u >> 16) & 1u);
  return (unsigned short)(u >> 16);
}

__device__ inline float bf2f(unsigned short h) {
  return __uint_as_float((unsigned int)h << 16);
}

__device__ inline void interp3(float v, float& u1, float& u2, float& u3) {
  const float sf = v * 3.3333333333333335f + 4.0f;   // (v+1.2)/0.3
  float fs = floorf(sf);
  fs = fminf(fmaxf(fs, 0.f), 7.f);
  const int   s  = (int)fs;
  const float fr = fminf(fmaxf(sf - fs, 0.f), 1.f);
  u1 = fmaf(fr, c_I1[s+1] - c_I1[s], c_I1[s]);
  u2 = fmaf(fr, c_I2[s+1] - c_I2[s], c_I2[s]);
  u3 = fmaf(fr, c_I3[s+1] - c_I3[s], c_I3[s]);
}

// branch-free coeff3: clamped ramps, differences, sign OR'd in.
__device__ inline void coeff3f(float g, float& c1, float& c2, float& c3) {
  const float    ga = fabsf(g);
  const unsigned sb = __float_as_uint(g) & 0x80000000u;
  const float t1 = fminf(ga * 1e4f, 1.f);
  const float t2 = fminf(fmaxf((ga - 1e-4f) * 5e3f, 0.f), 1.f);
  const float t3 = fmaxf((ga - 3e-4f) * 5e3f, 0.f);
  c1 = __uint_as_float(__float_as_uint(t1 - t2) | sb);
  c2 = __uint_as_float(__float_as_uint(t2 - t3) | sb);
  c3 = __uint_as_float(__float_as_uint(t3) | sb);
}

__device__ inline void coeff3(float g, float& c1, float& c2, float& c3) {
  const float ga  = fabsf(g);
  const float sgn = (g > 0.f) ? 1.f : ((g < 0.f) ? -1.f : 0.f);
  const int   idx = (ga >= 3e-4f) ? 2 : ((ga >= 1e-4f) ? 1 : 0);
  const float g0   = (idx == 0) ? 0.f : ((idx == 1) ? 1e-4f : 3e-4f);
  const float invd = (idx == 0) ? 1e4f : 5e3f;
  const float t    = (ga - g0) * invd;
  const float clo = sgn * (1.f - t), chi = sgn * t;
  c1 = (idx == 0) ? chi : ((idx == 1) ? clo : 0.f);
  c2 = (idx == 1) ? chi : ((idx == 2) ? clo : 0.f);
  c3 = (idx == 2) ? chi : 0.f;
}

// ---------------------------------------------------------------------------
// Dispatch 1: blocks 0..1023  -> per-block max(|w|,|b|) partials (no atomics)
//             blocks 1024..1167 -> prep U bf16 [128][KP4], k = 4*j + level
// ---------------------------------------------------------------------------
__global__ __launch_bounds__(256) void prep1_kernel(
    const float* __restrict__ x, const float* __restrict__ w,
    const float* __restrict__ bias, float* __restrict__ partials,
    unsigned short* __restrict__ Ub) {
  const int t = threadIdx.x, bid = blockIdx.x;
  if (bid < 1024) {                       // ---- maxabs partial ----
    const int i = bid * 256 + t;          // one float4 of w per thread
    const float4 v = ((const float4*)w)[i];
    float m = fmaxf(fmaxf(fabsf(v.x), fabsf(v.y)), fmaxf(fabsf(v.z), fabsf(v.w)));
    if (i < 256) {
      const float4 bv = ((const float4*)bias)[i];
      m = fmaxf(m, fmaxf(fmaxf(fabsf(bv.x), fabsf(bv.y)),
                         fmaxf(fabsf(bv.z), fabsf(bv.w))));
    }
    #pragma unroll
    for (int o = 32; o > 0; o >>= 1) m = fmaxf(m, __shfl_down(m, o, 64));
    __shared__ float red[4];
    if ((t & 63) == 0) red[t >> 6] = m;
    __syncthreads();
    if (t == 0)
      partials[bid] = fmaxf(fmaxf(red[0], red[1]), fmaxf(red[2], red[3]));
  } else {                                // ---- prep U ----
    const int idx = (bid - 1024) * 256 + t;   // 36864 = 128 b x 288 j4-groups
    const int b = idx / 288, j4 = idx - b * 288;
    ushort4 o0 = make_ushort4(0,0,0,0), o1 = o0, o2 = o0, o3 = o0;
    if (j4 < 256) {
      const float4 xv = ((const float4*)x)[b * 256 + j4];
      float u1, u2, u3;
      interp3(K_V_C * xv.x, u1, u2, u3); o0 = make_ushort4(f2bf(u1), f2bf(u2), f2bf(u3), 0);
      interp3(K_V_C * xv.y, u1, u2, u3); o1 = make_ushort4(f2bf(u1), f2bf(u2), f2bf(u3), 0);
      interp3(K_V_C * xv.z, u1, u2, u3); o2 = make_ushort4(f2bf(u1), f2bf(u2), f2bf(u3), 0);
      interp3(K_V_C * xv.w, u1, u2, u3); o3 = make_ushort4(f2bf(u1), f2bf(u2), f2bf(u3), 0);
    } else if (j4 == 256) {               // j = 1024: ones/bias column
      float u1, u2, u3;
      interp3(K_V_C, u1, u2, u3);
      o0 = make_ushort4(f2bf(u1), f2bf(u2), f2bf(u3), 0);
    }
    ushort4* dst = (ushort4*)(Ub + (size_t)b * KP4 + j4 * 16);
    dst[0] = o0; dst[1] = o1; dst[2] = o2; dst[3] = o3;
  }
}

// ---------------------------------------------------------------------------
// Dispatch 2: wide-N GEMM. 256 blocks (16 b x 32 m tile each) x 16 waves
//   (1024 thr), split-K x16 (288 k = 9 MFMA steps per wave). Per step ONE
//   A-fragment load feeds TWO MFMAs (cols n0+la and n0+16+la).
//   bf16 panel [1152 j][32 m] (72 KB; row 1024 = bias, 1025+ = 0, branch-free
//   inner loop). P[16][512] f32 (32 KB) aliases the panel for the K-reduce.
// ---------------------------------------------------------------------------
__global__ __launch_bounds__(1024, 4) void fusedgemm_kernel(
    const float* __restrict__ w, const float* __restrict__ bias,
    const float* __restrict__ partials, const unsigned short* __restrict__ Ub,
    float* __restrict__ out) {
  __shared__ __align__(16) unsigned short panel[36864];   // 72 KB: [1152][32]
  const int t = threadIdx.x;
  const int wv = t >> 6, lane = t & 63, la = lane & 15, kg = lane >> 4;
  const int b0 = (blockIdx.x >> 5) * 16;
  const int n0 = (blockIdx.x & 31) * 32;

  // ---- stage bf16 w-panel: panel[j][mm] = bf16(w[j][n0+mm]) ----
  #pragma unroll
  for (int i = 0; i < 8; ++i) {
    const int idx = i * 1024 + t;              // 8192 float4 of the w panel
    const int row = idx >> 3, c4 = idx & 7;    // row = j, 8 f4 per row
    const float4 v = *(const float4*)(w + (size_t)row * 1024 + n0 + c4 * 4);
    *(ushort4*)&panel[row * 32 + c4 * 4] =
        make_ushort4(f2bf(v.x), f2bf(v.y), f2bf(v.z), f2bf(v.w));
  }
  if (t < 32) panel[1024 * 32 + t] = f2bf(bias[n0 + t]);   // row 1024 = bias
  for (int i = 1025 * 32 + t; i < 1152 * 32; i += 1024) panel[i] = 0;

  // ---- maxw from all 1024 partials ----
  float mx = 0.f;
  #pragma unroll
  for (int i = 0; i < 4; ++i) {
    const float4 p = ((const float4*)partials)[lane + i * 64];
    mx = fmaxf(mx, fmaxf(fmaxf(p.x, p.y), fmaxf(p.z, p.w)));
  }
  #pragma unroll
  for (int o = 1; o < 64; o <<= 1) mx = fmaxf(mx, __shfl_xor(mx, o, 64));
  const float maxw = mx;
  const float kG   = G_DIFF / maxw;
  __syncthreads();

  // ---- 9-step branch-free MFMA loop (wave = k-slice of 288 = 72 j) ----
  const unsigned short* Ap = Ub + (size_t)(b0 + la) * KP4 + wv * 288 + kg * 8;
  const int jb = wv * 72 + kg * 2;
  f32x4 acc0 = {0.f, 0.f, 0.f, 0.f};
  f32x4 acc1 = {0.f, 0.f, 0.f, 0.f};
  #pragma unroll 3
  for (int ks = 0; ks < 9; ++ks) {
    const short8 a = *(const short8*)(Ap + ks * 32);
    const int j0 = jb + ks * 8;                // this lane's two j's: j0, j0+1
    const float w0a = bf2f(panel[j0 * 32 + la]);
    const float w0b = bf2f(panel[(j0 + 1) * 32 + la]);
    const float w1a = bf2f(panel[j0 * 32 + 16 + la]);
    const float w1b = bf2f(panel[(j0 + 1) * 32 + 16 + la]);
    float a1, a2, a3, b1, b2, b3, c1, c2, c3, d1, d2, d3;
    coeff3f(kG * w0a, a1, a2, a3);
    coeff3f(kG * w0b, b1, b2, b3);
    coeff3f(kG * w1a, c1, c2, c3);
    coeff3f(kG * w1b, d1, d2, d3);
    union { __hip_bfloat162 h[4]; short8 s; } bf0, bf1;
    bf0.h[0] = __float22bfloat162_rn(make_float2(a1, a2));
    bf0.h[1] = __float22bfloat162_rn(make_float2(a3, 0.f));
    bf0.h[2] = __float22bfloat162_rn(make_float2(b1, b2));
    bf0.h[3] = __float22bfloat162_rn(make_float2(b3, 0.f));
    bf1.h[0] = __float22bfloat162_rn(make_float2(c1, c2));
    bf1.h[1] = __float22bfloat162_rn(make_float2(c3, 0.f));
    bf1.h[2] = __float22bfloat162_rn(make_float2(d1, d2));
    bf1.h[3] = __float22bfloat162_rn(make_float2(d3, 0.f));
    acc0 = __builtin_amdgcn_mfma_f32_16x16x32_bf16(a, bf0.s, acc0, 0, 0, 0);
    acc1 = __builtin_amdgcn_mfma_f32_16x16x32_bf16(a, bf1.s, acc1, 0, 0, 0);
  }

  // ---- cross-wave K-reduce (P aliases the panel) + fused scale ----
  float* P = (float*)panel;                    // 32 KB < 72 KB, after barrier
  __syncthreads();                             // all waves done reading panel
  *(float4*)&P[wv * 512 + lane * 4]       = make_float4(acc0[0], acc0[1], acc0[2], acc0[3]);
  *(float4*)&P[wv * 512 + 256 + lane * 4] = make_float4(acc1[0], acc1[1], acc1[2], acc1[3]);
  __syncthreads();
  if (t < 512) {
    float s = 0.f;
    #pragma unroll
    for (int ww = 0; ww < 16; ++ww) s += P[ww * 512 + t];
    const int frag = t >> 8, f = t & 255;
    const int l2 = f >> 2, ai = f & 3;         // D: col = lane&15, row = kg*4+r
    const int row = b0 + ((l2 >> 4) << 2) + ai;
    const int col = n0 + frag * 16 + (l2 & 15);
    out[(size_t)row * 1024 + col] = s * (maxw * (1.0f / (K_V_C * G_DIFF)));
  }
}

// ---------------------------------------------------------------------------
// Fallback (tiny ws): atomic-based path, needs only 4 bytes of ws.
// ---------------------------------------------------------------------------
__global__ __launch_bounds__(256) void maxabs_atomic_kernel(
    const float* __restrict__ w, const float* __restrict__ b,
    unsigned int* __restrict__ wsmax) {
  const int NW4 = 262144, NB4 = 256;
  float m = 0.f;
  for (int i = blockIdx.x * blockDim.x + threadIdx.x; i < NW4 + NB4;
       i += gridDim.x * blockDim.x) {
    float4 v = (i < NW4) ? ((const float4*)w)[i] : ((const float4*)b)[i - NW4];
    m = fmaxf(m, fmaxf(fmaxf(fabsf(v.x), fabsf(v.y)),
                       fmaxf(fabsf(v.z), fabsf(v.w))));
  }
  #pragma unroll
  for (int o = 32; o > 0; o >>= 1) m = fmaxf(m, __shfl_down(m, o, 64));
  __shared__ float red[4];
  if ((threadIdx.x & 63) == 0) red[threadIdx.x >> 6] = m;
  __syncthreads();
  if (threadIdx.x == 0)
    atomicMax(wsmax, __float_as_uint(fmaxf(fmaxf(red[0], red[1]),
                                           fmaxf(red[2], red[3]))));
}

__global__ __launch_bounds__(256) void memristor_atomic_kernel(
    const float* __restrict__ x, const float* __restrict__ w,
    const float* __restrict__ bias, const unsigned int* __restrict__ wsmax,
    float* __restrict__ out) {
  __shared__ float4 U[2048];
  const int tid = threadIdx.x;
  const float maxw  = __uint_as_float(*wsmax);
  const float kG    = G_DIFF / maxw;
  const float scale = maxw * (1.0f / (K_V_C * G_DIFF));
  const int mq = tid & 15, bg = tid >> 4;
  const int m0 = blockIdx.x * 64 + mq * 4;
  const int swz = bg & 7;
  float acc[4][8];
  #pragma unroll
  for (int a = 0; a < 4; ++a)
    #pragma unroll
    for (int c = 0; c < 8; ++c) acc[a][c] = 0.f;
  for (int sc = blockIdx.y; sc < 65; sc += 16) {
    const int j0 = sc * 16;
    const int nj = min(16, 1025 - j0);
    __syncthreads();
    #pragma unroll
    for (int k = 0; k < 8; ++k) {
      const int e = k * 256 + tid;
      const int jl = e & 15, b = e >> 4;
      const int jg = j0 + jl;
      if (jg <= 1024) {
        const float v = (jg < 1024) ? K_V_C * x[b * 1024 + jg] : K_V_C;
        float u1, u2, u3;
        interp3(v, u1, u2, u3);
        U[b * 16 + (jl ^ ((b >> 3) & 7))] = make_float4(0.f, u1, u2, u3);
      }
    }
    __syncthreads();
    for (int jl = 0; jl < nj; ++jl) {
      const int jg = j0 + jl;
      const float4 wv = (jg < 1024) ? *(const float4*)(w + jg * 1024 + m0)
                                    : *(const float4*)(bias + m0);
      const float warr[4] = {wv.x, wv.y, wv.z, wv.w};
      float c1[4], c2[4], c3[4];
      #pragma unroll
      for (int mi = 0; mi < 4; ++mi) coeff3(kG * warr[mi], c1[mi], c2[mi], c3[mi]);
      const int base = bg * 128 + (jl ^ swz);
      #pragma unroll
      for (int bb = 0; bb < 8; ++bb) {
        const float4 u = U[base + bb * 16];
        #pragma unroll
        for (int mi = 0; mi < 4; ++mi)
          acc[mi][bb] = fmaf(c1[mi], u.y, fmaf(c2[mi], u.z, fmaf(c3[mi], u.w, acc[mi][bb])));
      }
    }
  }
  #pragma unroll
  for (int bb = 0; bb < 8; ++bb) {
    const int b = bg * 8 + bb;
    #pragma unroll
    for (int mi = 0; mi < 4; ++mi)
      atomicAdd(&out[b * 1024 + m0 + mi], acc[mi][bb] * scale);
  }
}

// ---------------------------------------------------------------------------
extern "C" void kernel_launch(void* const* d_in, const int* in_sizes, int n_in,
                              void* d_out, int out_size, void* d_ws, size_t ws_size,
                              hipStream_t stream) {
  const float* x = (const float*)d_in[0];   // (128, 1024)
  const float* w = (const float*)d_in[1];   // (1024, 1024)
  const float* b = (const float*)d_in[2];   // (1024,)
  float* out = (float*)d_out;               // (128, 1024) fp32

  float*          partials = (float*)((char*)d_ws + 128);        // 1024 f32
  unsigned short* Ub = (unsigned short*)((char*)d_ws + 8192);    // 1,179,648 B
  const size_t need = 8192 + (size_t)128 * KP4 * 2;              // ~1.13 MB

  if (ws_size >= need) {
    prep1_kernel<<<1168, 256, 0, stream>>>(x, w, b, partials, Ub);
    fusedgemm_kernel<<<256, 1024, 0, stream>>>(w, b, partials, Ub, out);
  } else {                                 // fallback: tiny ws, atomic path
    unsigned int* wsmax = (unsigned int*)d_ws;
    hipMemsetAsync(wsmax, 0, 4, stream);
    maxabs_atomic_kernel<<<256, 256, 0, stream>>>(w, b, wsmax);
    hipMemsetAsync(out, 0, (size_t)out_size * sizeof(float), stream);
    dim3 grid(16, 16);
    memristor_atomic_kernel<<<grid, 256, 0, stream>>>(x, w, b, wsmax, out);
  }
}